// Round 11
// baseline (589.711 us; speedup 1.0000x reference)
//
#include <hip/hip_runtime.h>
#include <hip/hip_bf16.h>

__device__ __forceinline__ float lrelu(float x){ return x >= 0.f ? x : 0.2f*x; }
__device__ __forceinline__ float sigm(float x){ return 1.f/(1.f+__expf(-x)); }

typedef short short8 __attribute__((ext_vector_type(8)));
typedef float f32x16 __attribute__((ext_vector_type(16)));

// ---------------- workspace layout (float offsets) ----------------
static constexpr size_t OFF_X0    = 0;          // 89*4096 = 364544
static constexpr size_t OFF_POS   = 475712;     // 16384  [h][i][d]
static constexpr size_t OFF_WQT   = 492096;     // 12288  [s][c][o]
static constexpr size_t OFF_STATS = 504384;     // 4 stages * 6 groups * 64 ch * {sum,ss} (raw sums)
static constexpr size_t OFF_P1    = 507456;     // 89*64*1024
static constexpr size_t OFF_P2    = 6340160;    // 89*64*256
static constexpr size_t OFF_RES   = 10714688;   // 89*64*256
static constexpr size_t OFF_MU    = 12172864;   // 320
static constexpr size_t OFF_COV   = 12173184;   // 5*64*64 (atomic-accumulated, zeroed in prep)
static constexpr size_t OFF_SIM   = 12193664;   // 64*5*256
static constexpr size_t OFF_R1    = 12275584;   // big overlaid region
static constexpr size_t OFF_C2    = OFF_R1;                 // 89*64*1024
static constexpr size_t OFF_C3    = OFF_R1 + 5832704;       // 89*64*256 (raw conv3)
static constexpr size_t OFF_C4    = OFF_R1 + 8749056;       // 89*64*256 (raw conv4)
static constexpr size_t OFF_CKV   = OFF_R1 + 10207232;      // 89*4*256*48 (packed {k,q,v})
static constexpr size_t OFF_MHRAW = OFF_R1 + 14581760;      // 89*64*256
static constexpr size_t OFF_QN    = OFF_R1 + 17543680;      // 64*64*256 -> ends at +21737984
static constexpr size_t OFF_WH    = OFF_R1 + 21737984;      // 36864 ushorts (18432 floats): conv2 w hi [9][och][cin]
static constexpr size_t OFF_WL    = OFF_WH + 18432;         // 36864 ushorts: conv2 w lo

__device__ __forceinline__ int bn_group(int img){ return (img < 64) ? 0 : (1 + (img-64)/5); }

__device__ __forceinline__ void bn_ab(const float* __restrict__ sums, int g, int c, float n,
                                      float gw, float bw, float& a, float& b)
{
    const float sum = sums[(g*64+c)*2], ss = sums[(g*64+c)*2+1];
    const float m = sum/n;
    const float var = fmaxf(ss/n - m*m, 0.f);
    const float istd = 1.f/sqrtf(var + 1e-5f);
    a = gw*istd;
    b = bw - m*a;
}

// ---------------- prep: pack inputs + pos + W^T + zero sums/cov + conv2 weight hi/lo split -----
__global__ __launch_bounds__(256) void prep_k(const float* __restrict__ in1, const float* __restrict__ in2,
        const float* __restrict__ relh, const float* __restrict__ relw,
        const float* __restrict__ wq, const float* __restrict__ wk, const float* __restrict__ wv,
        const float* __restrict__ cw2,
        float* __restrict__ ws)
{
    int idx = blockIdx.x*256 + threadIdx.x;
    if (idx < 364544) { ws[OFF_X0+idx] = (idx < 262144 ? in1[idx] : in2[idx-262144]); return; }
    idx -= 364544;
    if (idx < 16384) {
        const int h = idx>>12, r = idx&4095, i = r>>4, d = r&15;
        ws[OFF_POS+idx] = relh[h*256 + d*16 + (i&15)] + relw[h*256 + d*16 + (i>>4)];
        return;
    }
    idx -= 16384;
    if (idx < 12288) {
        const int s = idx/4096, r = idx%4096, c = r>>6, o = r&63;
        const float* wp = (s==0)?wq:((s==1)?wk:wv);
        ws[OFF_WQT+idx] = wp[o*64 + c];   // [s][c][o] = W[o][c]
        return;
    }
    idx -= 12288;
    if (idx < 3072) { ws[OFF_STATS+idx] = 0.f; return; }   // zero all 4 stages' sum/ss slots
    idx -= 3072;
    if (idx < 20480) { ws[OFF_COV+idx] = 0.f; return; }    // zero cov (atomic-accumulated)
    idx -= 20480;
    if (idx < 36864) {                                     // conv2 weights -> bf16 hi/lo [k9][och][cin]
        const int och = idx/576, r = idx%576, cin = r/9, k9 = r%9;
        const float v = cw2[idx];
        __hip_bfloat16 hb = __float2bfloat16(v);
        const float hv = __bfloat162float(hb);
        __hip_bfloat16 lb = __float2bfloat16(v - hv);
        unsigned short* WH = (unsigned short*)(ws + OFF_WH);
        unsigned short* WL = (unsigned short*)(ws + OFF_WL);
        const int d = k9*4096 + och*64 + cin;
        WH[d] = *(unsigned short*)&hb;
        WL[d] = *(unsigned short*)&lb;
    }
}

// ---------------- direct 3x3 conv (fp32) — used for conv1 stats, conv3, conv4 -------------------
template<int H, int W, int CIN, int CH, int OCB, int PT, bool STORE, bool INBN>
__global__ __launch_bounds__(256) void conv3x3_k(const float* __restrict__ in,
                                                 const float* __restrict__ wt,
                                                 float* __restrict__ out,
                                                 float* __restrict__ bnsum,
                                                 const float* __restrict__ isums,
                                                 const float* __restrict__ igw,
                                                 const float* __restrict__ ibw,
                                                 int ihw)
{
    constexpr int P = W + 1;
    constexpr int PLANE = H * P;
    constexpr int HW = H * W;
    constexpr int PASSES = HW / (256 * PT);
    constexpr int NLD = CH * HW / 256;      // staging loads per thread per chunk
    __shared__ float lds[CH * PLANE];
    __shared__ float redS[OCB*4], redQ[OCB*4];
    __shared__ float abA[64], abB[64];
    const int img = blockIdx.x;
    const int och0 = blockIdx.y * OCB;
    const int t = threadIdx.x;

    if constexpr (INBN) {
        if (t < CIN) {
            const int gi = bn_group(img);
            const float nin = (float)(((gi==0)?64:5) * ihw);
            float a, b;
            bn_ab(isums, gi, t, nin, igw[t], ibw[t], a, b);
            abA[t]=a; abB[t]=b;
        }
        __syncthreads();
    }

    float acc[PASSES][OCB][PT];
#pragma unroll
    for (int a=0;a<PASSES;a++)
#pragma unroll
      for (int o=0;o<OCB;o++)
#pragma unroll
        for (int p=0;p<PT;p++) acc[a][o][p]=0.f;

    // stage chunk 0 directly
    for (int idx = t; idx < CH*HW; idx += 256) {
        const int c = idx / HW, p = idx % HW;
        float v = in[((size_t)img*CIN + c)*HW + p];
        if constexpr (INBN) v = lrelu(abA[c]*v + abB[c]);
        lds[c*PLANE + (p/W)*P + (p%W)] = v;
    }
    __syncthreads();

    for (int cc0 = 0; cc0 < CIN; cc0 += CH) {
        float pre[(CIN > CH) ? NLD : 1];
        if constexpr (CIN > CH) {
            if (cc0 + CH < CIN) {
#pragma unroll
                for (int j=0;j<NLD;j++){
                    const int idx = j*256 + t;
                    const int c = idx / HW, p = idx % HW;
                    pre[j] = in[((size_t)img*CIN + cc0 + CH + c)*HW + p];
                }
            }
        }
        for (int c = 0; c < CH; ++c) {
            float wr[OCB][9];
#pragma unroll
            for (int o=0;o<OCB;o++)
#pragma unroll
              for (int k=0;k<9;k++)
                wr[o][k] = wt[((size_t)(och0+o)*CIN + (cc0+c))*9 + k];   // wave-uniform -> s_load
            const float* Lc = lds + c*PLANE;
#pragma unroll
            for (int ps=0; ps<PASSES; ++ps) {
                const int px0 = (ps*256 + t)*PT;
                const int y = px0 / W, x0 = px0 % W;
#pragma unroll
                for (int ky=0; ky<3; ++ky) {
                    const int yy = y + ky - 1;
                    if (yy >= 0 && yy < H) {
                        const float* Lr = Lc + yy*P;
                        float r[PT+2];
                        r[0] = (x0 > 0) ? Lr[x0-1] : 0.f;
#pragma unroll
                        for (int k2=0;k2<PT;k2++) r[k2+1] = Lr[x0+k2];
                        r[PT+1] = (x0+PT < W) ? Lr[x0+PT] : 0.f;
#pragma unroll
                        for (int p=0;p<PT;p++)
#pragma unroll
                          for (int kx=0;kx<3;kx++) {
                              const float v = r[p+kx];
#pragma unroll
                              for (int o=0;o<OCB;o++)
                                  acc[ps][o][p] += v * wr[o][ky*3+kx];
                          }
                    }
                }
            }
        }
        if constexpr (CIN > CH) {
            if (cc0 + CH < CIN) {
                __syncthreads();
#pragma unroll
                for (int j=0;j<NLD;j++){
                    const int idx = j*256 + t;
                    const int c = idx / HW, p = idx % HW;
                    float v = pre[j];
                    if constexpr (INBN) v = lrelu(abA[cc0+CH+c]*v + abB[cc0+CH+c]);
                    lds[c*PLANE + (p/W)*P + (p%W)] = v;
                }
                __syncthreads();
            }
        }
    }
    if constexpr (STORE) {
#pragma unroll
        for (int ps=0; ps<PASSES; ++ps) {
            const int px0 = (ps*256 + t)*PT;
#pragma unroll
            for (int o=0;o<OCB;o++)
#pragma unroll
              for (int p=0;p<PT;p++)
                out[((size_t)img*64 + och0+o)*HW + px0 + p] = acc[ps][o][p];
        }
    }
    const int g = bn_group(img);
    const int wv = t >> 6;
#pragma unroll
    for (int o=0;o<OCB;o++){
        float s=0.f, ss=0.f;
#pragma unroll
        for (int ps=0;ps<PASSES;ps++)
#pragma unroll
          for (int p=0;p<PT;p++){ const float v=acc[ps][o][p]; s+=v; ss+=v*v; }
#pragma unroll
        for (int off=32; off>0; off>>=1){ s += __shfl_xor(s, off); ss += __shfl_xor(ss, off); }
        if ((t&63)==0){ redS[o*4+wv]=s; redQ[o*4+wv]=ss; }
    }
    __syncthreads();
    if (t < OCB*2){
        const int o = t>>1, metric = t&1;
        const float v = metric ? (redQ[o*4]+redQ[o*4+1]+redQ[o*4+2]+redQ[o*4+3])
                               : (redS[o*4]+redS[o*4+1]+redS[o*4+2]+redS[o*4+3]);
        atomicAdd(&bnsum[(g*64 + och0+o)*2 + metric], v);
    }
}

// ---------------- conv2 via MFMA (bf16 hi/lo split, 9 shift-GEMMs, K=64 each) -------------------
// Block: (img, rowblk) -> 4 output rows x 32 cols (N=128), all 64 och (M=64).
// LDS: input rows rowblk*4-1..+4 as [ly][xp][c] bf16 hi+lo, pitch 72 (conflict-free b128 frags).
// A (weights) from global hi/lo [k9][och][cin] (L2-resident). acc: 2x mfma_32x32x16 tiles/wave.
__global__ __launch_bounds__(256) void conv2mfma_k(const float* __restrict__ p1,
        const unsigned short* __restrict__ whi, const unsigned short* __restrict__ wlo,
        float* __restrict__ c2)
{
    __shared__ __align__(16) unsigned short Bh[6*34*72];   // 29376 B
    __shared__ __align__(16) unsigned short Bl[6*34*72];   // 29376 B
    const int img = blockIdx.x, rowblk = blockIdx.y;
    const int t = threadIdx.x;

    // zero halo columns xp=0 and xp=33
    for (int i=t; i<6*2*72; i+=256){
        const int ly = i/144, r2 = i%144, xs = r2/72, c = r2%72;
        const int idx = (ly*34 + xs*33)*72 + c;
        Bh[idx]=0; Bl[idx]=0;
    }
    // stage 6 input rows (y0-1..y0+4), hi/lo split, pixel-major
    const int y0 = rowblk*4 - 1;
    for (int lin=t; lin<12288; lin+=256){
        const int c = lin/192, r = lin%192, ly = r>>5, x = r&31;
        const int y = y0 + ly;
        float v = 0.f;
        if (y>=0 && y<32) v = p1[((size_t)img*64 + c)*1024 + y*32 + x];
        __hip_bfloat16 hb = __float2bfloat16(v);
        const float hv = __bfloat162float(hb);
        __hip_bfloat16 lb = __float2bfloat16(v - hv);
        const int idx = (ly*34 + x + 1)*72 + c;
        Bh[idx] = *(unsigned short*)&hb;
        Bl[idx] = *(unsigned short*)&lb;
    }
    __syncthreads();

    const int lane = t & 63, wv = t >> 6;
    const int mt = wv & 1, ntp = wv >> 1;        // wave: m-tile (och 32-strip) x 2 n-tiles (rows)
    const int m = lane & 31, kg = lane >> 5;     // m/n within tile; k-group
    const int nt0 = ntp*2, nt1 = nt0 + 1;

    f32x16 acc0, acc1;
#pragma unroll
    for (int r=0;r<16;r++){ acc0[r]=0.f; acc1[r]=0.f; }

    for (int ky=0; ky<3; ky++){
      for (int kx=0; kx<3; kx++){
        const int s = ky*3 + kx;
        const unsigned short* wh = whi + ((s*64 + mt*32 + m)<<6) + kg*8;
        const unsigned short* wl = wlo + ((s*64 + mt*32 + m)<<6) + kg*8;
        const int b0 = ((nt0+ky)*34 + m + kx)*72 + kg*8;
        const int b1 = ((nt1+ky)*34 + m + kx)*72 + kg*8;
        short8 ah[4], al[4], bh0[4], bh1[4];
#pragma unroll
        for (int ch=0; ch<4; ch++){
            ah[ch]  = *(const short8*)(wh + ch*16);
            al[ch]  = *(const short8*)(wl + ch*16);
            bh0[ch] = *(const short8*)(Bh + b0 + ch*16);
            bh1[ch] = *(const short8*)(Bh + b1 + ch*16);
        }
#pragma unroll
        for (int ch=0; ch<4; ch++){
            acc0 = __builtin_amdgcn_mfma_f32_32x32x16_bf16(ah[ch], bh0[ch], acc0, 0,0,0);
            acc1 = __builtin_amdgcn_mfma_f32_32x32x16_bf16(ah[ch], bh1[ch], acc1, 0,0,0);
        }
#pragma unroll
        for (int ch=0; ch<4; ch++){
            acc0 = __builtin_amdgcn_mfma_f32_32x32x16_bf16(al[ch], bh0[ch], acc0, 0,0,0);
            acc1 = __builtin_amdgcn_mfma_f32_32x32x16_bf16(al[ch], bh1[ch], acc1, 0,0,0);
        }
#pragma unroll
        for (int ch=0; ch<4; ch++){
            const short8 bl0 = *(const short8*)(Bl + b0 + ch*16);
            const short8 bl1 = *(const short8*)(Bl + b1 + ch*16);
            acc0 = __builtin_amdgcn_mfma_f32_32x32x16_bf16(ah[ch], bl0, acc0, 0,0,0);
            acc1 = __builtin_amdgcn_mfma_f32_32x32x16_bf16(ah[ch], bl1, acc1, 0,0,0);
        }
      }
    }
    // C/D layout (verified m74/m101): och = (reg&3)+8*(reg>>2)+4*(lane>>5) within m-tile, px col = lane&31
    const int px0 = (rowblk*4 + nt0)*32 + m;
    const int px1 = (rowblk*4 + nt1)*32 + m;
#pragma unroll
    for (int r=0; r<16; r++){
        const int och = mt*32 + (r&3) + 8*(r>>2) + 4*kg;
        c2[((size_t)img*64 + och)*1024 + px0] = acc0[r];
        c2[((size_t)img*64 + och)*1024 + px1] = acc1[r];
    }
}

// ---------------- stage-2 BN sums from C2 (conv2mfma no longer carries stats) -------------------
__global__ __launch_bounds__(256) void bnstats2_k(const float* __restrict__ in, float* __restrict__ sums)
{
    __shared__ float rs[4], rq[4];
    const int img = blockIdx.x, c = blockIdx.y, t = threadIdx.x;
    const float4 v = ((const float4*)(in + ((size_t)img*64 + c)*1024))[t];
    float s = v.x+v.y+v.z+v.w;
    float q = v.x*v.x+v.y*v.y+v.z*v.z+v.w*v.w;
#pragma unroll
    for (int off=32; off>0; off>>=1){ s += __shfl_xor(s, off); q += __shfl_xor(q, off); }
    if ((t&63)==0){ rs[t>>6]=s; rq[t>>6]=q; }
    __syncthreads();
    if (t==0){
        const int g = bn_group(img);
        atomicAdd(&sums[(g*64+c)*2],   rs[0]+rs[1]+rs[2]+rs[3]);
        atomicAdd(&sums[(g*64+c)*2+1], rq[0]+rq[1]+rq[2]+rq[3]);
    }
}

// ---------------- stage 1 fused: recompute conv1 + BN + lrelu + 2x2 maxpool -> P1 ----------------
__global__ __launch_bounds__(256) void bnpoolconv1_k(const float* __restrict__ x0,
        const float* __restrict__ cw, const float* __restrict__ sums,
        const float* __restrict__ gw, const float* __restrict__ bw,
        float* __restrict__ out)   // [89][64][32][32]
{
    __shared__ float xl[64*65];  // 16.6 KB
    const int img = blockIdx.x, och = blockIdx.y, t = threadIdx.x;
    const float* xp = x0 + (size_t)img*4096;
    for (int idx=t; idx<4096; idx+=256) xl[(idx>>6)*65 + (idx&63)] = xp[idx];
    float w[9];
#pragma unroll
    for (int k=0;k<9;k++) w[k] = cw[och*9+k];   // wave-uniform -> s_load
    const int g = bn_group(img);
    const float n = (float)(((g==0)?64:5) * 4096);
    float a, b;
    bn_ab(sums, g, och, n, gw[och], bw[och], a, b);
    __syncthreads();
    const int oy = t>>3, ox0 = (t&7)*4;       // 32 rows x 8 groups of 4 output cols
    float r[4][10];
#pragma unroll
    for (int rr=0; rr<4; ++rr){
        const int yy = 2*oy-1+rr;
#pragma unroll
        for (int cc=0; cc<10; ++cc){
            const int xx = 2*ox0-1+cc;
            r[rr][cc] = (yy>=0 && yy<64 && xx>=0 && xx<64) ? xl[yy*65+xx] : 0.f;
        }
    }
    float4 res;
    float* rp = (float*)&res;
#pragma unroll
    for (int p=0;p<4;p++){
        float best = -1e30f;
#pragma unroll
        for (int sy=0; sy<2; ++sy)
#pragma unroll
          for (int sx=0; sx<2; ++sx){
            float s=0.f;
#pragma unroll
            for (int ky=0;ky<3;ky++)
#pragma unroll
              for (int kx=0;kx<3;kx++)
                s += r[sy+ky][2*p+sx+kx]*w[ky*3+kx];
            best = fmaxf(best, lrelu(a*s+b));
          }
        rp[p] = best;
    }
    *(float4*)(out + ((size_t)img*64+och)*1024 + oy*32 + ox0) = res;
}

template<int H, int W>
__global__ __launch_bounds__(256) void bnpool_k(const float* __restrict__ in, const float* __restrict__ sums,
                                 const float* __restrict__ gw, const float* __restrict__ bw,
                                 float* __restrict__ out)
{
    const int img = blockIdx.x, c = blockIdx.y, t = threadIdx.x;
    const int g = bn_group(img);
    const float n = (float)(((g==0)?64:5) * H * W);
    float a, b;
    bn_ab(sums, g, c, n, gw[c], bw[c], a, b);
    constexpr int W2=W/2, HW=H*W, N2=(H/2)*W2;
    const float* pl = in + ((size_t)img*64 + c)*HW;
    float* po = out + ((size_t)img*64 + c)*N2;
    for (int opx=t; opx<N2; opx+=256) {
        const int oy=opx/W2, ox=opx%W2;
        const float* q = pl + (2*oy)*W + 2*ox;
        const float v0=lrelu(a*q[0]+b), v1=lrelu(a*q[1]+b), v2=lrelu(a*q[W]+b), v3=lrelu(a*q[W+1]+b);
        po[opx] = fmaxf(fmaxf(v0,v1),fmaxf(v2,v3));
    }
}

// ---------------- MHSA projection: raw C4 in (BN4 inline) -> ckv[img][h][j][48] = {k,q,v} -------
__global__ __launch_bounds__(256) void proj_k(const float* __restrict__ c4, const float* __restrict__ wT,
               const float* __restrict__ bq, const float* __restrict__ bk, const float* __restrict__ bv,
               const float* __restrict__ sums4, const float* __restrict__ gw4, const float* __restrict__ bw4,
               float* __restrict__ ckv)
{
    __shared__ float xl[64*256];   // 64 KB exactly
    const int img = blockIdx.x, s = blockIdx.y, t = threadIdx.x;
    const int gi = bn_group(img);
    const float nin = (float)(((gi==0)?64:5) * 256);
    {
        const float4* in4 = (const float4*)(c4 + (size_t)img*16384);
        float4* xl4 = (float4*)xl;
        for (int i=t; i<4096; i+=256){
            float4 v = in4[i];
            const int c = i>>6;
            float a, b;
            bn_ab(sums4, gi, c, nin, gw4[c], bw4[c], a, b);
            v.x=lrelu(a*v.x+b); v.y=lrelu(a*v.y+b); v.z=lrelu(a*v.z+b); v.w=lrelu(a*v.w+b);
            xl4[i] = v;
        }
    }
    const float* bias = (s==0)?bq:((s==1)?bk:bv);
    const int sofs = (s==0)?16:((s==1)?0:32);      // q->16, k->0, v->32 within the 48-float row
    const float* wp = wT + s*4096;      // [c][o]
    const int o0 = (t>>4)*4, i0 = (t&15)*16;
    const int h = o0>>4, d0 = o0&15;
    __syncthreads();
    float acc[4][16];
    float b0[4];
#pragma unroll
    for (int o=0;o<4;o++) b0[o]=bias[o0+o];
#pragma unroll
    for (int o=0;o<4;o++)
#pragma unroll
      for (int i=0;i<16;i++) acc[o][i]=b0[o];
    for (int c=0;c<64;c++){
        const float4 w4 = *(const float4*)(wp + c*64 + o0);
        const float* xr = xl + c*256 + i0;
#pragma unroll
        for (int k=0;k<4;k++){
            const float4 x4 = *(const float4*)(xr + 4*k);
            acc[0][4*k+0]+=w4.x*x4.x; acc[0][4*k+1]+=w4.x*x4.y; acc[0][4*k+2]+=w4.x*x4.z; acc[0][4*k+3]+=w4.x*x4.w;
            acc[1][4*k+0]+=w4.y*x4.x; acc[1][4*k+1]+=w4.y*x4.y; acc[1][4*k+2]+=w4.y*x4.z; acc[1][4*k+3]+=w4.y*x4.w;
            acc[2][4*k+0]+=w4.z*x4.x; acc[2][4*k+1]+=w4.z*x4.y; acc[2][4*k+2]+=w4.z*x4.z; acc[2][4*k+3]+=w4.z*x4.w;
            acc[3][4*k+0]+=w4.w*x4.x; acc[3][4*k+1]+=w4.w*x4.y; acc[3][4*k+2]+=w4.w*x4.z; acc[3][4*k+3]+=w4.w*x4.w;
        }
    }
#pragma unroll
    for (int ii=0;ii<16;ii++){
        const float4 v = make_float4(acc[0][ii],acc[1][ii],acc[2][ii],acc[3][ii]);
        *(float4*)(ckv + (((size_t)img*4 + h)*256 + i0+ii)*48 + sofs + d0) = v;
    }
}

// ---------------- attention: online softmax, j-side via wave-uniform scalar loads, zero LDS ----------------
__global__ __launch_bounds__(256) void attn_k(const float* __restrict__ ckv, const float* __restrict__ pos,
                               float* __restrict__ mhraw)
{
    const int img = blockIdx.x, h = blockIdx.y, i = threadIdx.x;
    const size_t jb = (((size_t)img*4 + h)*256)*48;
    float areg[32];
    {
        const float* myrow = ckv + jb + (size_t)i*48;
#pragma unroll
        for (int k=0;k<4;k++) *(float4*)&areg[4*k]    = *(const float4*)(myrow + 16 + 4*k);  // q_i
#pragma unroll
        for (int k=0;k<4;k++) *(float4*)&areg[16+4*k] = *(const float4*)(pos + h*4096 + i*16 + 4*k); // pos_i
    }
    float mrun = -1e30f, l = 0.f;
    float accv[16];
#pragma unroll
    for (int d=0;d<16;d++) accv[d]=0.f;

    for (int j0=0; j0<256; j0+=2){
        const float* r0 = ckv + jb + (size_t)j0*48;      // wave-uniform -> s_load
        const float* r1 = r0 + 48;
        float s0a=0.f, s0b=0.f, s1a=0.f, s1b=0.f;
#pragma unroll
        for (int dd=0; dd<16; ++dd){
            s0a += areg[2*dd]  *r0[2*dd];
            s0b += areg[2*dd+1]*r0[2*dd+1];
            s1a += areg[2*dd]  *r1[2*dd];
            s1b += areg[2*dd+1]*r1[2*dd+1];
        }
        const float s0 = s0a+s0b, s1 = s1a+s1b;
        const float mnew = fmaxf(mrun, fmaxf(s0,s1));
        const float al = __expf(mrun - mnew);
        const float e0 = __expf(s0 - mnew), e1 = __expf(s1 - mnew);
        mrun = mnew;
        l = l*al + e0 + e1;
        const float* v0 = r0 + 32;
        const float* v1 = r1 + 32;
#pragma unroll
        for (int d=0;d<16;d++) accv[d] = accv[d]*al + e0*v0[d] + e1*v1[d];
    }
    const float rl = 1.f/l;
#pragma unroll
    for (int d=0;d<16;d++)
        mhraw[((size_t)img*64 + h*16 + d)*256 + i] = accv[d]*rl;
}

// ---------------- fused post-attention: mhsa-norm + CBAM + residual (raw C4 in, BN4 inline) -----
__global__ __launch_bounds__(256) void post_k(const float* __restrict__ mhraw,
        const float* __restrict__ lng, const float* __restrict__ lnb,
        const float* __restrict__ c4,
        const float* __restrict__ sums4, const float* __restrict__ gw4, const float* __restrict__ bw4,
        const float* __restrict__ w1, const float* __restrict__ b1,
        const float* __restrict__ w2, const float* __restrict__ b2,
        const float* __restrict__ sw, const float* __restrict__ sb,
        float* __restrict__ res)
{
    __shared__ float r1[256], r2[256];
    __shared__ float favg[64], fmx[64], z1s[8], ca[64];
    __shared__ float sf[512];
    __shared__ float wl[98];
    __shared__ float mh_s[2];
    __shared__ float aA[64], aB[64];
    __shared__ float sa_l[256];
    const int img = blockIdx.x, t = threadIdx.x;
    const float* mb  = mhraw + (size_t)img*16384;
    const float* fbr = c4    + (size_t)img*16384;

    if (t<64){
        const int gi = bn_group(img);
        const float nin = (float)(((gi==0)?64:5) * 256);
        float a, b;
        bn_ab(sums4, gi, t, nin, gw4[t], bw4[t], a, b);
        aA[t]=a; aB[t]=b;
    }
    if (t<98) wl[t] = sw[t];

    {
        const float4* mb4 = (const float4*)mb;
        float s=0.f, ss=0.f;
        for (int i=t; i<4096; i+=256){
            const float4 v = mb4[i];
            s  += v.x+v.y+v.z+v.w;
            ss += v.x*v.x+v.y*v.y+v.z*v.z+v.w*v.w;
        }
        r1[t]=s; r2[t]=ss; __syncthreads();
        for (int st=128;st>0;st>>=1){ if(t<st){r1[t]+=r1[t+st]; r2[t]+=r2[t+st];} __syncthreads(); }
        if (t==0){
            const float m = r1[0]/16384.f;
            const float var = fmaxf(r2[0]/16384.f - m*m, 0.f);
            mh_s[0]=m; mh_s[1]=1.f/sqrtf(var+1e-5f);
        }
    }
    {
        const int c = t>>2, part = t&3;
        const float a = aA[c], b = aB[c];
        const float4* p4 = (const float4*)(fbr + c*256 + part*64);
        float s=0.f, mx=-1e30f;
        for (int k=0;k<16;k++){
            const float4 v = p4[k];
            const float f0=lrelu(a*v.x+b), f1=lrelu(a*v.y+b), f2=lrelu(a*v.z+b), f3=lrelu(a*v.w+b);
            s += f0+f1+f2+f3;
            mx = fmaxf(mx, fmaxf(fmaxf(f0,f1),fmaxf(f2,f3)));
        }
        __syncthreads();
        r1[t]=s; r2[t]=mx;
        __syncthreads();
        if (t<64){
            favg[t] = (r1[t*4]+r1[t*4+1]+r1[t*4+2]+r1[t*4+3])/256.f;
            fmx[t]  = fmaxf(fmaxf(r2[t*4],r2[t*4+1]),fmaxf(r2[t*4+2],r2[t*4+3]));
        }
    }
    __syncthreads();
    if (t<8){
        const int which = t>>2, o = t&3;
        const float* f = which? fmx : favg;
        float z = b1[o];
        for (int c=0;c<64;c++) z += w1[o*64+c]*f[c];
        z1s[t] = fmaxf(z, 0.f);
    }
    __syncthreads();
    if (t<64){
        float z = 2.f*b2[t];
#pragma unroll
        for (int k=0;k<4;k++) z += w2[t*4+k]*(z1s[k]+z1s[4+k]);
        ca[t] = sigm(z);
    }
    __syncthreads();
    {
        float s=0.f, mx=-1e30f;
        for (int c=0;c<64;c++){
            const float fv = lrelu(aA[c]*fbr[c*256+t] + aB[c]);
            const float v = ca[c]*fv;
            s += v; mx = fmaxf(mx, v);
        }
        sf[t]     = s/64.f;
        sf[256+t] = mx;
    }
    __syncthreads();
    {
        float sacc = sb[0];
        const int y = t>>4, x = t&15;
        for (int ch=0; ch<2; ++ch)
          for (int ky=0; ky<7; ++ky){
            const int yy = y+ky-3;
            if (yy<0||yy>=16) continue;
            for (int kx=0; kx<7; ++kx){
                const int xx = x+kx-3;
                if (xx<0||xx>=16) continue;
                sacc += sf[ch*256 + yy*16 + xx]*wl[ch*49 + ky*7 + kx];
            }
          }
        sa_l[t] = sigm(sacc);
    }
    __syncthreads();
    {
        const int q = t & 63;
        const int cb = t >> 6;
        const float m = mh_s[0], istd = mh_s[1];
        const float4* mb4 = (const float4*)mb;
        const float4* fb4 = (const float4*)fbr;
        const float4* lg4 = (const float4*)lng;
        const float4* lb4 = (const float4*)lnb;
        float4* res4 = (float4*)(res + (size_t)img*16384);
        const float sa0=sa_l[4*q], sa1=sa_l[4*q+1], sa2=sa_l[4*q+2], sa3=sa_l[4*q+3];
#pragma unroll 4
        for (int cc=0; cc<16; ++cc){
            const int c = cb*16 + cc;
            const int i4 = c*64 + q;
            const float4 mv = mb4[i4], fv = fb4[i4], gv = lg4[i4], bv = lb4[i4];
            const float a = aA[c], b = aB[c], cf = ca[c];
            float4 r;
            r.x = (mv.x-m)*istd*gv.x + bv.x + lrelu(a*fv.x+b)*(2.f + sa0*cf);
            r.y = (mv.y-m)*istd*gv.y + bv.y + lrelu(a*fv.y+b)*(2.f + sa1*cf);
            r.z = (mv.z-m)*istd*gv.z + bv.z + lrelu(a*fv.z+b)*(2.f + sa2*cf);
            r.w = (mv.w-m)*istd*gv.w + bv.w + lrelu(a*fv.w+b)*(2.f + sa3*cf);
            res4[i4] = r;
        }
    }
}

// ---------------- covariance ----------------
__global__ __launch_bounds__(256) void covmu_k(const float* __restrict__ res, float* __restrict__ mu)
{
    __shared__ float r1[256];
    const int n = blockIdx.x, c = blockIdx.y, t = threadIdx.x;
    float s=0.f;
    for (int sh=0; sh<5; ++sh)
        s += res[((size_t)(64 + n*5 + sh)*64 + c)*256 + t];
    r1[t]=s; __syncthreads();
    for (int st=128;st>0;st>>=1){ if(t<st) r1[t]+=r1[t+st]; __syncthreads(); }
    if (t==0) mu[n*64+c] = r1[0]/1280.f;
}

__global__ __launch_bounds__(256) void cov_k(const float* __restrict__ res, const float* __restrict__ mu,
                                             float* __restrict__ cov)
{
    __shared__ float Xl[64*129];   // 33 KB
    const int n = blockIdx.x, by = blockIdx.y, sh = blockIdx.z, t = threadIdx.x;
    const int c = by*16 + (t>>4);
    const int d0 = (t&15)*4;
    float acc[4] = {0.f,0.f,0.f,0.f};
    for (int half=0; half<2; ++half){
        __syncthreads();
        for (int idx=t; idx<8192; idx+=256){
            const int ch = idx>>7, p = idx&127;
            Xl[ch*129+p] = res[((size_t)(64+n*5+sh)*64 + ch)*256 + half*128 + p] - mu[n*64+ch];
        }
        __syncthreads();
        for (int p=0;p<128;p++){
            const float xc = Xl[c*129+p];
#pragma unroll
            for (int k=0;k<4;k++) acc[k] += xc*Xl[(d0+k)*129+p];
        }
    }
#pragma unroll
    for (int k=0;k<4;k++) atomicAdd(&cov[((size_t)n*64 + c)*64 + d0+k], acc[k]*(1.f/1279.f));
}

// ---------------- Q normalize over hw per (b,c) ----------------
__global__ __launch_bounds__(64) void qn_k(const float* __restrict__ res, float* __restrict__ qn)
{
    const int b = blockIdx.x, c = blockIdx.y, t = threadIdx.x;
    const size_t base = ((size_t)b*64 + c)*256;
    const float4 v = *(const float4*)(res + base + t*4);
    float ss = v.x*v.x + v.y*v.y + v.z*v.z + v.w*v.w;
#pragma unroll
    for (int off=32; off>0; off>>=1) ss += __shfl_xor(ss, off);
    const float inv = 1.f/sqrtf(ss);
    float4 o; o.x=v.x*inv; o.y=v.y*inv; o.z=v.z*inv; o.w=v.w*inv;
    *(float4*)(qn + base + t*4) = o;
}

// ---------------- sim[b,j,i] = Qn(:,i)^T cov_j Qn(:,i) ----------------
__global__ __launch_bounds__(256) void sim_k(const float* __restrict__ qn, const float* __restrict__ cov,
                                             float* __restrict__ sim)
{
    __shared__ float covj[64*65];
    __shared__ float Vl[64*68];
    __shared__ float simred[320];
    const int b = blockIdx.x, iq = blockIdx.y, t = threadIdx.x;
    const int i0g = iq*64;
    for (int idx=t; idx<4096; idx+=256){
        const int c = idx>>6, il = idx&63;
        Vl[c*68+il] = qn[((size_t)b*64+c)*256 + i0g + il];
    }
    for (int idx=t; idx<320; idx+=256) simred[idx]=0.f;
    const int c0 = (t>>4)*4, i0 = (t&15)*4;
    for (int j=0;j<5;j++){
        __syncthreads();
        for (int idx=t; idx<4096; idx+=256)
            covj[(idx>>6)*65 + (idx&63)] = cov[(size_t)j*4096 + idx];
        __syncthreads();
        float pt[4][4];
#pragma unroll
        for (int a=0;a<4;a++)
#pragma unroll
          for (int bb=0;bb<4;bb++) pt[a][bb]=0.f;
        for (int d=0; d<64; ++d){
            const float4 vv = *(const float4*)&Vl[d*68 + i0];
            float cw[4];
#pragma unroll
            for (int cc=0;cc<4;cc++) cw[cc] = covj[(c0+cc)*65 + d];
#pragma unroll
            for (int cc=0;cc<4;cc++){
                pt[cc][0] += cw[cc]*vv.x;
                pt[cc][1] += cw[cc]*vv.y;
                pt[cc][2] += cw[cc]*vv.z;
                pt[cc][3] += cw[cc]*vv.w;
            }
        }
#pragma unroll
        for (int ii=0;ii<4;ii++){
            float s = 0.f;
#pragma unroll
            for (int cc=0;cc<4;cc++) s += pt[cc][ii]*Vl[(c0+cc)*68 + i0+ii];
            atomicAdd(&simred[j*64 + i0 + ii], s);
        }
    }
    __syncthreads();
    for (int idx=t; idx<320; idx+=256){
        const int j = idx>>6, il = idx&63;
        sim[((size_t)b*5 + j)*256 + i0g + il] = simred[idx];
    }
}

// ---------------- classifier ----------------
__global__ __launch_bounds__(256) void cls_k(const float* __restrict__ sim, const float* __restrict__ cw,
                                             float* __restrict__ out)
{
    __shared__ float red[256];
    const int b = blockIdx.x, t = threadIdx.x;
    const float w = cw[t];
    for (int j=0;j<5;j++){
        const float v = sim[((size_t)b*5 + j)*256 + t];
        red[t] = lrelu(v)*w;
        __syncthreads();
        for (int st=128;st>0;st>>=1){ if(t<st) red[t]+=red[t+st]; __syncthreads(); }
        if (t==0) out[b*5+j] = red[0];
        __syncthreads();
    }
}

// ---------------- launch ----------------
extern "C" void kernel_launch(void* const* d_in, const int* in_sizes, int n_in,
                              void* d_out, int out_size, void* d_ws, size_t ws_size,
                              hipStream_t stream)
{
    const float* IN[31];
    for (int i=0;i<31;i++) IN[i] = (const float*)d_in[i];
    float* W = (float*)d_ws;
    float* OUT = (float*)d_out;
    const unsigned short* WHp = (const unsigned short*)(W + OFF_WH);
    const unsigned short* WLp = (const unsigned short*)(W + OFF_WL);

    prep_k<<<1772,256,0,stream>>>(IN[0],IN[1],IN[20],IN[21],IN[14],IN[16],IN[18],IN[5],W);

    // stage 1: conv1 stats-only -> fused recompute+BN+pool
    conv3x3_k<64,64,1,1,4,4,false,false><<<dim3(89,16),256,0,stream>>>(W+OFF_X0, IN[2], nullptr, W+OFF_STATS, nullptr,nullptr,nullptr,0);
    bnpoolconv1_k<<<dim3(89,64),256,0,stream>>>(W+OFF_X0, IN[2], W+OFF_STATS, IN[3], IN[4], W+OFF_P1);

    // stage 2: MFMA conv2 (bf16 hi/lo) -> stats pass -> BN/lrelu/pool -> P2
    conv2mfma_k<<<dim3(89,8),256,0,stream>>>(W+OFF_P1, WHp, WLp, W+OFF_C2);
    bnstats2_k<<<dim3(89,64),256,0,stream>>>(W+OFF_C2, W+OFF_STATS+768);
    bnpool_k<32,32><<<dim3(89,64),256,0,stream>>>(W+OFF_C2, W+OFF_STATS+768, IN[6], IN[7], W+OFF_P2);

    // stage 3: conv3(+stats) -> raw C3 (BN3 applied inline by conv4)
    conv3x3_k<16,16,64,16,8,1,true,false><<<dim3(89,8),256,0,stream>>>(W+OFF_P2, IN[8], W+OFF_C3, W+OFF_STATS+1536, nullptr,nullptr,nullptr,0);

    // stage 4: conv4 with BN3 inline on input -> raw C4 (BN4 applied inline by proj/post)
    conv3x3_k<16,16,64,16,8,1,true,true><<<dim3(89,8),256,0,stream>>>(W+OFF_C3, IN[11], W+OFF_C4, W+OFF_STATS+2304,
                                                                      W+OFF_STATS+1536, IN[9], IN[10], 256);

    // MHSA (BN4 inline in proj)
    proj_k<<<dim3(89,3),256,0,stream>>>(W+OFF_C4, W+OFF_WQT, IN[15], IN[17], IN[19],
                                        W+OFF_STATS+2304, IN[12], IN[13], W+OFF_CKV);
    attn_k<<<dim3(89,4),256,0,stream>>>(W+OFF_CKV, W+OFF_POS, W+OFF_MHRAW);

    // fused mhsa-norm + CBAM + residual (BN4 inline)
    post_k<<<89,256,0,stream>>>(W+OFF_MHRAW, IN[22], IN[23], W+OFF_C4,
                                W+OFF_STATS+2304, IN[12], IN[13],
                                IN[24], IN[25], IN[26], IN[27], IN[28], IN[29], W+OFF_RES);

    // covariance metric + classifier
    covmu_k<<<dim3(5,64),256,0,stream>>>(W+OFF_RES, W+OFF_MU);
    cov_k<<<dim3(5,4,5),256,0,stream>>>(W+OFF_RES, W+OFF_MU, W+OFF_COV);
    qn_k<<<dim3(64,64),64,0,stream>>>(W+OFF_RES, W+OFF_QN);
    sim_k<<<dim3(64,4),256,0,stream>>>(W+OFF_QN, W+OFF_COV, W+OFF_SIM);
    cls_k<<<64,256,0,stream>>>(W+OFF_SIM, IN[30], OUT);
}

// Round 12
// 538.698 us; speedup vs baseline: 1.0947x; 1.0947x over previous
//
#include <hip/hip_runtime.h>
#include <hip/hip_bf16.h>

__device__ __forceinline__ float lrelu(float x){ return x >= 0.f ? x : 0.2f*x; }
__device__ __forceinline__ float sigm(float x){ return 1.f/(1.f+__expf(-x)); }

typedef short short8 __attribute__((ext_vector_type(8)));
typedef float f32x16 __attribute__((ext_vector_type(16)));

// ---------------- workspace layout (float offsets) ----------------
static constexpr size_t OFF_X0    = 0;          // 89*4096 = 364544
static constexpr size_t OFF_POS   = 475712;     // 16384  [h][i][d]
static constexpr size_t OFF_WQT   = 492096;     // 12288  [s][c][o]
static constexpr size_t OFF_STATS = 504384;     // 4 stages * 6 groups * 64 ch * {sum,ss} (raw sums)
static constexpr size_t OFF_P1    = 507456;     // 89*64*1024
static constexpr size_t OFF_P2    = 6340160;    // 89*64*256
static constexpr size_t OFF_RES   = 10714688;   // 89*64*256
static constexpr size_t OFF_MU    = 12172864;   // 320
static constexpr size_t OFF_COV   = 12173184;   // 5*64*64 (atomic-accumulated, zeroed in prep)
static constexpr size_t OFF_SIM   = 12193664;   // 64*5*256
static constexpr size_t OFF_R1    = 12275584;   // big overlaid region
static constexpr size_t OFF_C2    = OFF_R1;                 // 89*64*1024
static constexpr size_t OFF_ATP   = OFF_R1;                 // attn partials 89*4*4*18*256=6.56M (C2/C3 dead by then)
static constexpr size_t OFF_C3    = OFF_R1 + 5832704;       // 89*64*256 (raw conv3)
static constexpr size_t OFF_C4    = OFF_R1 + 8749056;       // 89*64*256 (raw conv4)
static constexpr size_t OFF_CKV   = OFF_R1 + 10207232;      // 89*4*256*48 (packed {k,q,v})
static constexpr size_t OFF_MHRAW = OFF_R1 + 14581760;      // 89*64*256
static constexpr size_t OFF_QN    = OFF_R1 + 17543680;      // 64*64*256 -> ends at +21737984
static constexpr size_t OFF_WH    = OFF_R1 + 21737984;      // 36864 ushorts: conv2 w hi [9][och][cin]
static constexpr size_t OFF_WL    = OFF_WH + 18432;         // 36864 ushorts: conv2 w lo

__device__ __forceinline__ int bn_group(int img){ return (img < 64) ? 0 : (1 + (img-64)/5); }

__device__ __forceinline__ void bn_ab(const float* __restrict__ sums, int g, int c, float n,
                                      float gw, float bw, float& a, float& b)
{
    const float sum = sums[(g*64+c)*2], ss = sums[(g*64+c)*2+1];
    const float m = sum/n;
    const float var = fmaxf(ss/n - m*m, 0.f);
    const float istd = 1.f/sqrtf(var + 1e-5f);
    a = gw*istd;
    b = bw - m*a;
}

// ---------------- prep: pack inputs + pos + W^T + zero sums/cov + conv2 weight hi/lo split -----
__global__ __launch_bounds__(256) void prep_k(const float* __restrict__ in1, const float* __restrict__ in2,
        const float* __restrict__ relh, const float* __restrict__ relw,
        const float* __restrict__ wq, const float* __restrict__ wk, const float* __restrict__ wv,
        const float* __restrict__ cw2,
        float* __restrict__ ws)
{
    int idx = blockIdx.x*256 + threadIdx.x;
    if (idx < 364544) { ws[OFF_X0+idx] = (idx < 262144 ? in1[idx] : in2[idx-262144]); return; }
    idx -= 364544;
    if (idx < 16384) {
        const int h = idx>>12, r = idx&4095, i = r>>4, d = r&15;
        ws[OFF_POS+idx] = relh[h*256 + d*16 + (i&15)] + relw[h*256 + d*16 + (i>>4)];
        return;
    }
    idx -= 16384;
    if (idx < 12288) {
        const int s = idx/4096, r = idx%4096, c = r>>6, o = r&63;
        const float* wp = (s==0)?wq:((s==1)?wk:wv);
        ws[OFF_WQT+idx] = wp[o*64 + c];   // [s][c][o] = W[o][c]
        return;
    }
    idx -= 12288;
    if (idx < 3072) { ws[OFF_STATS+idx] = 0.f; return; }   // zero all 4 stages' sum/ss slots
    idx -= 3072;
    if (idx < 20480) { ws[OFF_COV+idx] = 0.f; return; }    // zero cov (atomic-accumulated)
    idx -= 20480;
    if (idx < 36864) {                                     // conv2 weights -> bf16 hi/lo [k9][och][cin]
        const int och = idx/576, r = idx%576, cin = r/9, k9 = r%9;
        const float v = cw2[idx];
        __hip_bfloat16 hb = __float2bfloat16(v);
        const float hv = __bfloat162float(hb);
        __hip_bfloat16 lb = __float2bfloat16(v - hv);
        unsigned short* WH = (unsigned short*)(ws + OFF_WH);
        unsigned short* WL = (unsigned short*)(ws + OFF_WL);
        const int d = k9*4096 + och*64 + cin;
        WH[d] = *(unsigned short*)&hb;
        WL[d] = *(unsigned short*)&lb;
    }
}

// ---------------- direct 3x3 conv (fp32) — used for conv1 stats, conv3, conv4 -------------------
template<int H, int W, int CIN, int CH, int OCB, int PT, bool STORE, bool INBN>
__global__ __launch_bounds__(256) void conv3x3_k(const float* __restrict__ in,
                                                 const float* __restrict__ wt,
                                                 float* __restrict__ out,
                                                 float* __restrict__ bnsum,
                                                 const float* __restrict__ isums,
                                                 const float* __restrict__ igw,
                                                 const float* __restrict__ ibw,
                                                 int ihw)
{
    constexpr int P = W + 1;
    constexpr int PLANE = H * P;
    constexpr int HW = H * W;
    constexpr int PASSES = HW / (256 * PT);
    constexpr int NLD = CH * HW / 256;      // staging loads per thread per chunk
    __shared__ float lds[CH * PLANE];
    __shared__ float redS[OCB*4], redQ[OCB*4];
    __shared__ float abA[64], abB[64];
    const int img = blockIdx.x;
    const int och0 = blockIdx.y * OCB;
    const int t = threadIdx.x;

    if constexpr (INBN) {
        if (t < CIN) {
            const int gi = bn_group(img);
            const float nin = (float)(((gi==0)?64:5) * ihw);
            float a, b;
            bn_ab(isums, gi, t, nin, igw[t], ibw[t], a, b);
            abA[t]=a; abB[t]=b;
        }
        __syncthreads();
    }

    float acc[PASSES][OCB][PT];
#pragma unroll
    for (int a=0;a<PASSES;a++)
#pragma unroll
      for (int o=0;o<OCB;o++)
#pragma unroll
        for (int p=0;p<PT;p++) acc[a][o][p]=0.f;

    // stage chunk 0 directly
    for (int idx = t; idx < CH*HW; idx += 256) {
        const int c = idx / HW, p = idx % HW;
        float v = in[((size_t)img*CIN + c)*HW + p];
        if constexpr (INBN) v = lrelu(abA[c]*v + abB[c]);
        lds[c*PLANE + (p/W)*P + (p%W)] = v;
    }
    __syncthreads();

    for (int cc0 = 0; cc0 < CIN; cc0 += CH) {
        float pre[(CIN > CH) ? NLD : 1];
        if constexpr (CIN > CH) {
            if (cc0 + CH < CIN) {
#pragma unroll
                for (int j=0;j<NLD;j++){
                    const int idx = j*256 + t;
                    const int c = idx / HW, p = idx % HW;
                    pre[j] = in[((size_t)img*CIN + cc0 + CH + c)*HW + p];
                }
            }
        }
        for (int c = 0; c < CH; ++c) {
            float wr[OCB][9];
#pragma unroll
            for (int o=0;o<OCB;o++)
#pragma unroll
              for (int k=0;k<9;k++)
                wr[o][k] = wt[((size_t)(och0+o)*CIN + (cc0+c))*9 + k];   // wave-uniform -> s_load
            const float* Lc = lds + c*PLANE;
#pragma unroll
            for (int ps=0; ps<PASSES; ++ps) {
                const int px0 = (ps*256 + t)*PT;
                const int y = px0 / W, x0 = px0 % W;
#pragma unroll
                for (int ky=0; ky<3; ++ky) {
                    const int yy = y + ky - 1;
                    if (yy >= 0 && yy < H) {
                        const float* Lr = Lc + yy*P;
                        float r[PT+2];
                        r[0] = (x0 > 0) ? Lr[x0-1] : 0.f;
#pragma unroll
                        for (int k2=0;k2<PT;k2++) r[k2+1] = Lr[x0+k2];
                        r[PT+1] = (x0+PT < W) ? Lr[x0+PT] : 0.f;
#pragma unroll
                        for (int p=0;p<PT;p++)
#pragma unroll
                          for (int kx=0;kx<3;kx++) {
                              const float v = r[p+kx];
#pragma unroll
                              for (int o=0;o<OCB;o++)
                                  acc[ps][o][p] += v * wr[o][ky*3+kx];
                          }
                    }
                }
            }
        }
        if constexpr (CIN > CH) {
            if (cc0 + CH < CIN) {
                __syncthreads();
#pragma unroll
                for (int j=0;j<NLD;j++){
                    const int idx = j*256 + t;
                    const int c = idx / HW, p = idx % HW;
                    float v = pre[j];
                    if constexpr (INBN) v = lrelu(abA[cc0+CH+c]*v + abB[cc0+CH+c]);
                    lds[c*PLANE + (p/W)*P + (p%W)] = v;
                }
                __syncthreads();
            }
        }
    }
    if constexpr (STORE) {
#pragma unroll
        for (int ps=0; ps<PASSES; ++ps) {
            const int px0 = (ps*256 + t)*PT;
#pragma unroll
            for (int o=0;o<OCB;o++)
#pragma unroll
              for (int p=0;p<PT;p++)
                out[((size_t)img*64 + och0+o)*HW + px0 + p] = acc[ps][o][p];
        }
    }
    const int g = bn_group(img);
    const int wv = t >> 6;
#pragma unroll
    for (int o=0;o<OCB;o++){
        float s=0.f, ss=0.f;
#pragma unroll
        for (int ps=0;ps<PASSES;ps++)
#pragma unroll
          for (int p=0;p<PT;p++){ const float v=acc[ps][o][p]; s+=v; ss+=v*v; }
#pragma unroll
        for (int off=32; off>0; off>>=1){ s += __shfl_xor(s, off); ss += __shfl_xor(ss, off); }
        if ((t&63)==0){ redS[o*4+wv]=s; redQ[o*4+wv]=ss; }
    }
    __syncthreads();
    if (t < OCB*2){
        const int o = t>>1, metric = t&1;
        const float v = metric ? (redQ[o*4]+redQ[o*4+1]+redQ[o*4+2]+redQ[o*4+3])
                               : (redS[o*4]+redS[o*4+1]+redS[o*4+2]+redS[o*4+3]);
        atomicAdd(&bnsum[(g*64 + och0+o)*2 + metric], v);
    }
}

// ---------------- conv2 via MFMA — R12: single 29.4 KB LDS buffer, two phases (hi then lo) ------
// lo input bits stashed packed in 24 VGPRs between phases -> 3+ blocks/CU instead of 2.
__global__ __launch_bounds__(256) void conv2mfma_k(const float* __restrict__ p1,
        const unsigned short* __restrict__ whi, const unsigned short* __restrict__ wlo,
        float* __restrict__ c2)
{
    __shared__ __align__(16) unsigned short Bx[6*34*72];   // 29376 B
    const int img = blockIdx.x, rowblk = blockIdx.y;
    const int t = threadIdx.x;

    // zero halo columns xp=0 and xp=33
    for (int i=t; i<6*2*72; i+=256){
        const int ly = i/144, r2 = i%144, xs = r2/72, c = r2%72;
        Bx[(ly*34 + xs*33)*72 + c] = 0;
    }
    // stage hi; stash lo packed 2-per-VGPR
    unsigned int lo_pack[24];
    const int y0 = rowblk*4 - 1;
    {
        int it = 0;
        for (int lin=t; lin<12288; lin+=256, ++it){
            const int c = lin/192, r = lin%192, ly = r>>5, x = r&31;
            const int y = y0 + ly;
            float v = 0.f;
            if (y>=0 && y<32) v = p1[((size_t)img*64 + c)*1024 + y*32 + x];
            __hip_bfloat16 hb = __float2bfloat16(v);
            const float hv = __bfloat162float(hb);
            __hip_bfloat16 lb = __float2bfloat16(v - hv);
            Bx[(ly*34 + x + 1)*72 + c] = *(unsigned short*)&hb;
            const unsigned int lu = *(unsigned short*)&lb;
            if (it & 1) lo_pack[it>>1] |= (lu<<16); else lo_pack[it>>1] = lu;
        }
    }
    __syncthreads();

    const int lane = t & 63, wv = t >> 6;
    const int mt = wv & 1, ntp = wv >> 1;
    const int m = lane & 31, kg = lane >> 5;
    const int nt0 = ntp*2, nt1 = nt0 + 1;

    f32x16 acc0, acc1;
#pragma unroll
    for (int r=0;r<16;r++){ acc0[r]=0.f; acc1[r]=0.f; }

    // phase 1: Ah*Bh + Al*Bh
    for (int ky=0; ky<3; ky++){
      for (int kx=0; kx<3; kx++){
        const int s = ky*3 + kx;
        const unsigned short* wh = whi + ((s*64 + mt*32 + m)<<6) + kg*8;
        const unsigned short* wl = wlo + ((s*64 + mt*32 + m)<<6) + kg*8;
        const int b0 = ((nt0+ky)*34 + m + kx)*72 + kg*8;
        const int b1 = ((nt1+ky)*34 + m + kx)*72 + kg*8;
        short8 ah[4], al[4], bh0[4], bh1[4];
#pragma unroll
        for (int ch=0; ch<4; ch++){
            ah[ch]  = *(const short8*)(wh + ch*16);
            al[ch]  = *(const short8*)(wl + ch*16);
            bh0[ch] = *(const short8*)(Bx + b0 + ch*16);
            bh1[ch] = *(const short8*)(Bx + b1 + ch*16);
        }
#pragma unroll
        for (int ch=0; ch<4; ch++){
            acc0 = __builtin_amdgcn_mfma_f32_32x32x16_bf16(ah[ch], bh0[ch], acc0, 0,0,0);
            acc1 = __builtin_amdgcn_mfma_f32_32x32x16_bf16(ah[ch], bh1[ch], acc1, 0,0,0);
        }
#pragma unroll
        for (int ch=0; ch<4; ch++){
            acc0 = __builtin_amdgcn_mfma_f32_32x32x16_bf16(al[ch], bh0[ch], acc0, 0,0,0);
            acc1 = __builtin_amdgcn_mfma_f32_32x32x16_bf16(al[ch], bh1[ch], acc1, 0,0,0);
        }
      }
    }
    __syncthreads();
    // restage lo from register stash
    {
        int it = 0;
        for (int lin=t; lin<12288; lin+=256, ++it){
            const int c = lin/192, r = lin%192, ly = r>>5, x = r&31;
            const unsigned int lu = (it&1) ? (lo_pack[it>>1]>>16) : (lo_pack[it>>1]&0xffffu);
            Bx[(ly*34 + x + 1)*72 + c] = (unsigned short)lu;
        }
    }
    __syncthreads();
    // phase 2: Ah*Bl
    for (int ky=0; ky<3; ky++){
      for (int kx=0; kx<3; kx++){
        const int s = ky*3 + kx;
        const unsigned short* wh = whi + ((s*64 + mt*32 + m)<<6) + kg*8;
        const int b0 = ((nt0+ky)*34 + m + kx)*72 + kg*8;
        const int b1 = ((nt1+ky)*34 + m + kx)*72 + kg*8;
#pragma unroll
        for (int ch=0; ch<4; ch++){
            const short8 ah  = *(const short8*)(wh + ch*16);
            const short8 bl0 = *(const short8*)(Bx + b0 + ch*16);
            const short8 bl1 = *(const short8*)(Bx + b1 + ch*16);
            acc0 = __builtin_amdgcn_mfma_f32_32x32x16_bf16(ah, bl0, acc0, 0,0,0);
            acc1 = __builtin_amdgcn_mfma_f32_32x32x16_bf16(ah, bl1, acc1, 0,0,0);
        }
      }
    }
    // C/D layout (verified m74/m101): och = (reg&3)+8*(reg>>2)+4*kg within m-tile, px col = lane&31
    const int px0 = (rowblk*4 + nt0)*32 + m;
    const int px1 = (rowblk*4 + nt1)*32 + m;
#pragma unroll
    for (int r=0; r<16; r++){
        const int och = mt*32 + (r&3) + 8*(r>>2) + 4*kg;
        c2[((size_t)img*64 + och)*1024 + px0] = acc0[r];
        c2[((size_t)img*64 + och)*1024 + px1] = acc1[r];
    }
}

// ---------------- stage-2 BN sums from C2 ----------------
__global__ __launch_bounds__(256) void bnstats2_k(const float* __restrict__ in, float* __restrict__ sums)
{
    __shared__ float rs[4], rq[4];
    const int img = blockIdx.x, c = blockIdx.y, t = threadIdx.x;
    const float4 v = ((const float4*)(in + ((size_t)img*64 + c)*1024))[t];
    float s = v.x+v.y+v.z+v.w;
    float q = v.x*v.x+v.y*v.y+v.z*v.z+v.w*v.w;
#pragma unroll
    for (int off=32; off>0; off>>=1){ s += __shfl_xor(s, off); q += __shfl_xor(q, off); }
    if ((t&63)==0){ rs[t>>6]=s; rq[t>>6]=q; }
    __syncthreads();
    if (t==0){
        const int g = bn_group(img);
        atomicAdd(&sums[(g*64+c)*2],   rs[0]+rs[1]+rs[2]+rs[3]);
        atomicAdd(&sums[(g*64+c)*2+1], rq[0]+rq[1]+rq[2]+rq[3]);
    }
}

// ---------------- stage 1 fused: recompute conv1 + BN + lrelu + 2x2 maxpool -> P1 ----------------
__global__ __launch_bounds__(256) void bnpoolconv1_k(const float* __restrict__ x0,
        const float* __restrict__ cw, const float* __restrict__ sums,
        const float* __restrict__ gw, const float* __restrict__ bw,
        float* __restrict__ out)   // [89][64][32][32]
{
    __shared__ float xl[64*65];  // 16.6 KB
    const int img = blockIdx.x, och = blockIdx.y, t = threadIdx.x;
    const float* xp = x0 + (size_t)img*4096;
    for (int idx=t; idx<4096; idx+=256) xl[(idx>>6)*65 + (idx&63)] = xp[idx];
    float w[9];
#pragma unroll
    for (int k=0;k<9;k++) w[k] = cw[och*9+k];   // wave-uniform -> s_load
    const int g = bn_group(img);
    const float n = (float)(((g==0)?64:5) * 4096);
    float a, b;
    bn_ab(sums, g, och, n, gw[och], bw[och], a, b);
    __syncthreads();
    const int oy = t>>3, ox0 = (t&7)*4;
    float r[4][10];
#pragma unroll
    for (int rr=0; rr<4; ++rr){
        const int yy = 2*oy-1+rr;
#pragma unroll
        for (int cc=0; cc<10; ++cc){
            const int xx = 2*ox0-1+cc;
            r[rr][cc] = (yy>=0 && yy<64 && xx>=0 && xx<64) ? xl[yy*65+xx] : 0.f;
        }
    }
    float4 res;
    float* rp = (float*)&res;
#pragma unroll
    for (int p=0;p<4;p++){
        float best = -1e30f;
#pragma unroll
        for (int sy=0; sy<2; ++sy)
#pragma unroll
          for (int sx=0; sx<2; ++sx){
            float s=0.f;
#pragma unroll
            for (int ky=0;ky<3;ky++)
#pragma unroll
              for (int kx=0;kx<3;kx++)
                s += r[sy+ky][2*p+sx+kx]*w[ky*3+kx];
            best = fmaxf(best, lrelu(a*s+b));
          }
        rp[p] = best;
    }
    *(float4*)(out + ((size_t)img*64+och)*1024 + oy*32 + ox0) = res;
}

template<int H, int W>
__global__ __launch_bounds__(256) void bnpool_k(const float* __restrict__ in, const float* __restrict__ sums,
                                 const float* __restrict__ gw, const float* __restrict__ bw,
                                 float* __restrict__ out)
{
    const int img = blockIdx.x, c = blockIdx.y, t = threadIdx.x;
    const int g = bn_group(img);
    const float n = (float)(((g==0)?64:5) * H * W);
    float a, b;
    bn_ab(sums, g, c, n, gw[c], bw[c], a, b);
    constexpr int W2=W/2, HW=H*W, N2=(H/2)*W2;
    const float* pl = in + ((size_t)img*64 + c)*HW;
    float* po = out + ((size_t)img*64 + c)*N2;
    for (int opx=t; opx<N2; opx+=256) {
        const int oy=opx/W2, ox=opx%W2;
        const float* q = pl + (2*oy)*W + 2*ox;
        const float v0=lrelu(a*q[0]+b), v1=lrelu(a*q[1]+b), v2=lrelu(a*q[W]+b), v3=lrelu(a*q[W+1]+b);
        po[opx] = fmaxf(fmaxf(v0,v1),fmaxf(v2,v3));
    }
}

// ---------------- MHSA projection: raw C4 in (BN4 inline) -> ckv[img][h][j][48] = {k,q,v} -------
__global__ __launch_bounds__(256) void proj_k(const float* __restrict__ c4, const float* __restrict__ wT,
               const float* __restrict__ bq, const float* __restrict__ bk, const float* __restrict__ bv,
               const float* __restrict__ sums4, const float* __restrict__ gw4, const float* __restrict__ bw4,
               float* __restrict__ ckv)
{
    __shared__ float xl[64*256];   // 64 KB exactly
    const int img = blockIdx.x, s = blockIdx.y, t = threadIdx.x;
    const int gi = bn_group(img);
    const float nin = (float)(((gi==0)?64:5) * 256);
    {
        const float4* in4 = (const float4*)(c4 + (size_t)img*16384);
        float4* xl4 = (float4*)xl;
        for (int i=t; i<4096; i+=256){
            float4 v = in4[i];
            const int c = i>>6;
            float a, b;
            bn_ab(sums4, gi, c, nin, gw4[c], bw4[c], a, b);
            v.x=lrelu(a*v.x+b); v.y=lrelu(a*v.y+b); v.z=lrelu(a*v.z+b); v.w=lrelu(a*v.w+b);
            xl4[i] = v;
        }
    }
    const float* bias = (s==0)?bq:((s==1)?bk:bv);
    const int sofs = (s==0)?16:((s==1)?0:32);
    const float* wp = wT + s*4096;      // [c][o]
    const int o0 = (t>>4)*4, i0 = (t&15)*16;
    const int h = o0>>4, d0 = o0&15;
    __syncthreads();
    float acc[4][16];
    float b0[4];
#pragma unroll
    for (int o=0;o<4;o++) b0[o]=bias[o0+o];
#pragma unroll
    for (int o=0;o<4;o++)
#pragma unroll
      for (int i=0;i<16;i++) acc[o][i]=b0[o];
    for (int c=0;c<64;c++){
        const float4 w4 = *(const float4*)(wp + c*64 + o0);
        const float* xr = xl + c*256 + i0;
#pragma unroll
        for (int k=0;k<4;k++){
            const float4 x4 = *(const float4*)(xr + 4*k);
            acc[0][4*k+0]+=w4.x*x4.x; acc[0][4*k+1]+=w4.x*x4.y; acc[0][4*k+2]+=w4.x*x4.z; acc[0][4*k+3]+=w4.x*x4.w;
            acc[1][4*k+0]+=w4.y*x4.x; acc[1][4*k+1]+=w4.y*x4.y; acc[1][4*k+2]+=w4.y*x4.z; acc[1][4*k+3]+=w4.y*x4.w;
            acc[2][4*k+0]+=w4.z*x4.x; acc[2][4*k+1]+=w4.z*x4.y; acc[2][4*k+2]+=w4.z*x4.z; acc[2][4*k+3]+=w4.z*x4.w;
            acc[3][4*k+0]+=w4.w*x4.x; acc[3][4*k+1]+=w4.w*x4.y; acc[3][4*k+2]+=w4.w*x4.z; acc[3][4*k+3]+=w4.w*x4.w;
        }
    }
#pragma unroll
    for (int ii=0;ii<16;ii++){
        const float4 v = make_float4(acc[0][ii],acc[1][ii],acc[2][ii],acc[3][ii]);
        *(float4*)(ckv + (((size_t)img*4 + h)*256 + i0+ii)*48 + sofs + d0) = v;
    }
}

// ---------------- attention partial: j-chunk flash pass (4 chunks of 64 j) ----------------------
// part layout per (img,h,jc): 18 fields x 256 i  (f=0:m, f=1:l, f=2+d:acc[d]) — coalesced
__global__ __launch_bounds__(256) void attnp_k(const float* __restrict__ ckv, const float* __restrict__ pos,
                               float* __restrict__ part)
{
    const int img = blockIdx.x, h = blockIdx.y, jc = blockIdx.z, i = threadIdx.x;
    const size_t jb = (((size_t)img*4 + h)*256)*48;
    float areg[32];
    {
        const float* myrow = ckv + jb + (size_t)i*48;
#pragma unroll
        for (int k=0;k<4;k++) *(float4*)&areg[4*k]    = *(const float4*)(myrow + 16 + 4*k);  // q_i
#pragma unroll
        for (int k=0;k<4;k++) *(float4*)&areg[16+4*k] = *(const float4*)(pos + h*4096 + i*16 + 4*k); // pos_i
    }
    float mrun = -1e30f, l = 0.f;
    float accv[16];
#pragma unroll
    for (int d=0;d<16;d++) accv[d]=0.f;

    const int jend = jc*64 + 64;
    for (int j0=jc*64; j0<jend; j0+=2){
        const float* r0 = ckv + jb + (size_t)j0*48;      // wave-uniform -> s_load
        const float* r1 = r0 + 48;
        float s0a=0.f, s0b=0.f, s1a=0.f, s1b=0.f;
#pragma unroll
        for (int dd=0; dd<16; ++dd){
            s0a += areg[2*dd]  *r0[2*dd];
            s0b += areg[2*dd+1]*r0[2*dd+1];
            s1a += areg[2*dd]  *r1[2*dd];
            s1b += areg[2*dd+1]*r1[2*dd+1];
        }
        const float s0 = s0a+s0b, s1 = s1a+s1b;
        const float mnew = fmaxf(mrun, fmaxf(s0,s1));
        const float al = __expf(mrun - mnew);
        const float e0 = __expf(s0 - mnew), e1 = __expf(s1 - mnew);
        mrun = mnew;
        l = l*al + e0 + e1;
        const float* v0 = r0 + 32;
        const float* v1 = r1 + 32;
#pragma unroll
        for (int d=0;d<16;d++) accv[d] = accv[d]*al + e0*v0[d] + e1*v1[d];
    }
    float* pp = part + ((((size_t)img*4 + h)*4 + jc)*18)*256;
    pp[i]       = mrun;
    pp[256 + i] = l;
#pragma unroll
    for (int d=0;d<16;d++) pp[(2+d)*256 + i] = accv[d];
}

// ---------------- attention merge: combine 4 j-chunk partials --------------------------------
__global__ __launch_bounds__(256) void attnm_k(const float* __restrict__ part, float* __restrict__ mhraw)
{
    const int img = blockIdx.x, h = blockIdx.y, i = threadIdx.x;
    const float* pb = part + (((size_t)img*4 + h)*4*18)*256;
    float mc[4], lc[4];
#pragma unroll
    for (int c=0;c<4;c++){ mc[c] = pb[c*4608 + i]; lc[c] = pb[c*4608 + 256 + i]; }
    const float ms = fmaxf(fmaxf(mc[0],mc[1]), fmaxf(mc[2],mc[3]));
    float wgt[4]; float ls = 0.f;
#pragma unroll
    for (int c=0;c<4;c++){ wgt[c] = __expf(mc[c]-ms); ls += wgt[c]*lc[c]; }
    const float rl = 1.f/ls;
#pragma unroll
    for (int d=0;d<16;d++){
        float v = 0.f;
#pragma unroll
        for (int c=0;c<4;c++) v += wgt[c]*pb[c*4608 + (2+d)*256 + i];
        mhraw[((size_t)img*64 + h*16 + d)*256 + i] = v*rl;
    }
}

// ---------------- fused post-attention: mhsa-norm + CBAM + residual (raw C4 in, BN4 inline) -----
__global__ __launch_bounds__(256) void post_k(const float* __restrict__ mhraw,
        const float* __restrict__ lng, const float* __restrict__ lnb,
        const float* __restrict__ c4,
        const float* __restrict__ sums4, const float* __restrict__ gw4, const float* __restrict__ bw4,
        const float* __restrict__ w1, const float* __restrict__ b1,
        const float* __restrict__ w2, const float* __restrict__ b2,
        const float* __restrict__ sw, const float* __restrict__ sb,
        float* __restrict__ res)
{
    __shared__ float r1[256], r2[256];
    __shared__ float favg[64], fmx[64], z1s[8], ca[64];
    __shared__ float sf[512];
    __shared__ float wl[98];
    __shared__ float mh_s[2];
    __shared__ float aA[64], aB[64];
    __shared__ float sa_l[256];
    const int img = blockIdx.x, t = threadIdx.x;
    const float* mb  = mhraw + (size_t)img*16384;
    const float* fbr = c4    + (size_t)img*16384;

    if (t<64){
        const int gi = bn_group(img);
        const float nin = (float)(((gi==0)?64:5) * 256);
        float a, b;
        bn_ab(sums4, gi, t, nin, gw4[t], bw4[t], a, b);
        aA[t]=a; aB[t]=b;
    }
    if (t<98) wl[t] = sw[t];

    {
        const float4* mb4 = (const float4*)mb;
        float s=0.f, ss=0.f;
        for (int i=t; i<4096; i+=256){
            const float4 v = mb4[i];
            s  += v.x+v.y+v.z+v.w;
            ss += v.x*v.x+v.y*v.y+v.z*v.z+v.w*v.w;
        }
        r1[t]=s; r2[t]=ss; __syncthreads();
        for (int st=128;st>0;st>>=1){ if(t<st){r1[t]+=r1[t+st]; r2[t]+=r2[t+st];} __syncthreads(); }
        if (t==0){
            const float m = r1[0]/16384.f;
            const float var = fmaxf(r2[0]/16384.f - m*m, 0.f);
            mh_s[0]=m; mh_s[1]=1.f/sqrtf(var+1e-5f);
        }
    }
    {
        const int c = t>>2, part = t&3;
        const float a = aA[c], b = aB[c];
        const float4* p4 = (const float4*)(fbr + c*256 + part*64);
        float s=0.f, mx=-1e30f;
        for (int k=0;k<16;k++){
            const float4 v = p4[k];
            const float f0=lrelu(a*v.x+b), f1=lrelu(a*v.y+b), f2=lrelu(a*v.z+b), f3=lrelu(a*v.w+b);
            s += f0+f1+f2+f3;
            mx = fmaxf(mx, fmaxf(fmaxf(f0,f1),fmaxf(f2,f3)));
        }
        __syncthreads();
        r1[t]=s; r2[t]=mx;
        __syncthreads();
        if (t<64){
            favg[t] = (r1[t*4]+r1[t*4+1]+r1[t*4+2]+r1[t*4+3])/256.f;
            fmx[t]  = fmaxf(fmaxf(r2[t*4],r2[t*4+1]),fmaxf(r2[t*4+2],r2[t*4+3]));
        }
    }
    __syncthreads();
    if (t<8){
        const int which = t>>2, o = t&3;
        const float* f = which? fmx : favg;
        float z = b1[o];
        for (int c=0;c<64;c++) z += w1[o*64+c]*f[c];
        z1s[t] = fmaxf(z, 0.f);
    }
    __syncthreads();
    if (t<64){
        float z = 2.f*b2[t];
#pragma unroll
        for (int k=0;k<4;k++) z += w2[t*4+k]*(z1s[k]+z1s[4+k]);
        ca[t] = sigm(z);
    }
    __syncthreads();
    {
        float s=0.f, mx=-1e30f;
        for (int c=0;c<64;c++){
            const float fv = lrelu(aA[c]*fbr[c*256+t] + aB[c]);
            const float v = ca[c]*fv;
            s += v; mx = fmaxf(mx, v);
        }
        sf[t]     = s/64.f;
        sf[256+t] = mx;
    }
    __syncthreads();
    {
        float sacc = sb[0];
        const int y = t>>4, x = t&15;
        for (int ch=0; ch<2; ++ch)
          for (int ky=0; ky<7; ++ky){
            const int yy = y+ky-3;
            if (yy<0||yy>=16) continue;
            for (int kx=0; kx<7; ++kx){
                const int xx = x+kx-3;
                if (xx<0||xx>=16) continue;
                sacc += sf[ch*256 + yy*16 + xx]*wl[ch*49 + ky*7 + kx];
            }
          }
        sa_l[t] = sigm(sacc);
    }
    __syncthreads();
    {
        const int q = t & 63;
        const int cb = t >> 6;
        const float m = mh_s[0], istd = mh_s[1];
        const float4* mb4 = (const float4*)mb;
        const float4* fb4 = (const float4*)fbr;
        const float4* lg4 = (const float4*)lng;
        const float4* lb4 = (const float4*)lnb;
        float4* res4 = (float4*)(res + (size_t)img*16384);
        const float sa0=sa_l[4*q], sa1=sa_l[4*q+1], sa2=sa_l[4*q+2], sa3=sa_l[4*q+3];
#pragma unroll 4
        for (int cc=0; cc<16; ++cc){
            const int c = cb*16 + cc;
            const int i4 = c*64 + q;
            const float4 mv = mb4[i4], fv = fb4[i4], gv = lg4[i4], bv = lb4[i4];
            const float a = aA[c], b = aB[c], cf = ca[c];
            float4 r;
            r.x = (mv.x-m)*istd*gv.x + bv.x + lrelu(a*fv.x+b)*(2.f + sa0*cf);
            r.y = (mv.y-m)*istd*gv.y + bv.y + lrelu(a*fv.y+b)*(2.f + sa1*cf);
            r.z = (mv.z-m)*istd*gv.z + bv.z + lrelu(a*fv.z+b)*(2.f + sa2*cf);
            r.w = (mv.w-m)*istd*gv.w + bv.w + lrelu(a*fv.w+b)*(2.f + sa3*cf);
            res4[i4] = r;
        }
    }
}

// ---------------- covariance ----------------
__global__ __launch_bounds__(256) void covmu_k(const float* __restrict__ res, float* __restrict__ mu)
{
    __shared__ float r1[256];
    const int n = blockIdx.x, c = blockIdx.y, t = threadIdx.x;
    float s=0.f;
    for (int sh=0; sh<5; ++sh)
        s += res[((size_t)(64 + n*5 + sh)*64 + c)*256 + t];
    r1[t]=s; __syncthreads();
    for (int st=128;st>0;st>>=1){ if(t<st) r1[t]+=r1[t+st]; __syncthreads(); }
    if (t==0) mu[n*64+c] = r1[0]/1280.f;
}

__global__ __launch_bounds__(256) void cov_k(const float* __restrict__ res, const float* __restrict__ mu,
                                             float* __restrict__ cov)
{
    __shared__ float Xl[64*129];   // 33 KB
    const int n = blockIdx.x, by = blockIdx.y, sh = blockIdx.z, t = threadIdx.x;
    const int c = by*16 + (t>>4);
    const int d0 = (t&15)*4;
    float acc[4] = {0.f,0.f,0.f,0.f};
    for (int half=0; half<2; ++half){
        __syncthreads();
        for (int idx=t; idx<8192; idx+=256){
            const int ch = idx>>7, p = idx&127;
            Xl[ch*129+p] = res[((size_t)(64+n*5+sh)*64 + ch)*256 + half*128 + p] - mu[n*64+ch];
        }
        __syncthreads();
        for (int p=0;p<128;p++){
            const float xc = Xl[c*129+p];
#pragma unroll
            for (int k=0;k<4;k++) acc[k] += xc*Xl[(d0+k)*129+p];
        }
    }
#pragma unroll
    for (int k=0;k<4;k++) atomicAdd(&cov[((size_t)n*64 + c)*64 + d0+k], acc[k]*(1.f/1279.f));
}

// ---------------- Q normalize over hw per (b,c) ----------------
__global__ __launch_bounds__(64) void qn_k(const float* __restrict__ res, float* __restrict__ qn)
{
    const int b = blockIdx.x, c = blockIdx.y, t = threadIdx.x;
    const size_t base = ((size_t)b*64 + c)*256;
    const float4 v = *(const float4*)(res + base + t*4);
    float ss = v.x*v.x + v.y*v.y + v.z*v.z + v.w*v.w;
#pragma unroll
    for (int off=32; off>0; off>>=1) ss += __shfl_xor(ss, off);
    const float inv = 1.f/sqrtf(ss);
    float4 o; o.x=v.x*inv; o.y=v.y*inv; o.z=v.z*inv; o.w=v.w*inv;
    *(float4*)(qn + base + t*4) = o;
}

// ---------------- sim[b,j,i] = Qn(:,i)^T cov_j Qn(:,i) ----------------
__global__ __launch_bounds__(256) void sim_k(const float* __restrict__ qn, const float* __restrict__ cov,
                                             float* __restrict__ sim)
{
    __shared__ float covj[64*65];
    __shared__ float Vl[64*68];
    __shared__ float simred[320];
    const int b = blockIdx.x, iq = blockIdx.y, t = threadIdx.x;
    const int i0g = iq*64;
    for (int idx=t; idx<4096; idx+=256){
        const int c = idx>>6, il = idx&63;
        Vl[c*68+il] = qn[((size_t)b*64+c)*256 + i0g + il];
    }
    for (int idx=t; idx<320; idx+=256) simred[idx]=0.f;
    const int c0 = (t>>4)*4, i0 = (t&15)*4;
    for (int j=0;j<5;j++){
        __syncthreads();
        for (int idx=t; idx<4096; idx+=256)
            covj[(idx>>6)*65 + (idx&63)] = cov[(size_t)j*4096 + idx];
        __syncthreads();
        float pt[4][4];
#pragma unroll
        for (int a=0;a<4;a++)
#pragma unroll
          for (int bb=0;bb<4;bb++) pt[a][bb]=0.f;
        for (int d=0; d<64; ++d){
            const float4 vv = *(const float4*)&Vl[d*68 + i0];
            float cw[4];
#pragma unroll
            for (int cc=0;cc<4;cc++) cw[cc] = covj[(c0+cc)*65 + d];
#pragma unroll
            for (int cc=0;cc<4;cc++){
                pt[cc][0] += cw[cc]*vv.x;
                pt[cc][1] += cw[cc]*vv.y;
                pt[cc][2] += cw[cc]*vv.z;
                pt[cc][3] += cw[cc]*vv.w;
            }
        }
#pragma unroll
        for (int ii=0;ii<4;ii++){
            float s = 0.f;
#pragma unroll
            for (int cc=0;cc<4;cc++) s += pt[cc][ii]*Vl[(c0+cc)*68 + i0+ii];
            atomicAdd(&simred[j*64 + i0 + ii], s);
        }
    }
    __syncthreads();
    for (int idx=t; idx<320; idx+=256){
        const int j = idx>>6, il = idx&63;
        sim[((size_t)b*5 + j)*256 + i0g + il] = simred[idx];
    }
}

// ---------------- classifier ----------------
__global__ __launch_bounds__(256) void cls_k(const float* __restrict__ sim, const float* __restrict__ cw,
                                             float* __restrict__ out)
{
    __shared__ float red[256];
    const int b = blockIdx.x, t = threadIdx.x;
    const float w = cw[t];
    for (int j=0;j<5;j++){
        const float v = sim[((size_t)b*5 + j)*256 + t];
        red[t] = lrelu(v)*w;
        __syncthreads();
        for (int st=128;st>0;st>>=1){ if(t<st) red[t]+=red[t+st]; __syncthreads(); }
        if (t==0) out[b*5+j] = red[0];
        __syncthreads();
    }
}

// ---------------- launch ----------------
extern "C" void kernel_launch(void* const* d_in, const int* in_sizes, int n_in,
                              void* d_out, int out_size, void* d_ws, size_t ws_size,
                              hipStream_t stream)
{
    const float* IN[31];
    for (int i=0;i<31;i++) IN[i] = (const float*)d_in[i];
    float* W = (float*)d_ws;
    float* OUT = (float*)d_out;
    const unsigned short* WHp = (const unsigned short*)(W + OFF_WH);
    const unsigned short* WLp = (const unsigned short*)(W + OFF_WL);

    prep_k<<<1772,256,0,stream>>>(IN[0],IN[1],IN[20],IN[21],IN[14],IN[16],IN[18],IN[5],W);

    // stage 1: conv1 stats-only -> fused recompute+BN+pool
    conv3x3_k<64,64,1,1,4,4,false,false><<<dim3(89,16),256,0,stream>>>(W+OFF_X0, IN[2], nullptr, W+OFF_STATS, nullptr,nullptr,nullptr,0);
    bnpoolconv1_k<<<dim3(89,64),256,0,stream>>>(W+OFF_X0, IN[2], W+OFF_STATS, IN[3], IN[4], W+OFF_P1);

    // stage 2: MFMA conv2 (two-phase hi/lo, 29 KB LDS) -> stats -> BN/lrelu/pool -> P2
    conv2mfma_k<<<dim3(89,8),256,0,stream>>>(W+OFF_P1, WHp, WLp, W+OFF_C2);
    bnstats2_k<<<dim3(89,64),256,0,stream>>>(W+OFF_C2, W+OFF_STATS+768);
    bnpool_k<32,32><<<dim3(89,64),256,0,stream>>>(W+OFF_C2, W+OFF_STATS+768, IN[6], IN[7], W+OFF_P2);

    // stage 3: conv3(+stats) -> raw C3 (BN3 applied inline by conv4)
    conv3x3_k<16,16,64,16,8,1,true,false><<<dim3(89,8),256,0,stream>>>(W+OFF_P2, IN[8], W+OFF_C3, W+OFF_STATS+1536, nullptr,nullptr,nullptr,0);

    // stage 4: conv4 with BN3 inline on input -> raw C4 (BN4 applied inline by proj/post)
    conv3x3_k<16,16,64,16,8,1,true,true><<<dim3(89,8),256,0,stream>>>(W+OFF_C3, IN[11], W+OFF_C4, W+OFF_STATS+2304,
                                                                      W+OFF_STATS+1536, IN[9], IN[10], 256);

    // MHSA (BN4 inline in proj); attention split into 4 j-chunks + merge
    proj_k<<<dim3(89,3),256,0,stream>>>(W+OFF_C4, W+OFF_WQT, IN[15], IN[17], IN[19],
                                        W+OFF_STATS+2304, IN[12], IN[13], W+OFF_CKV);
    attnp_k<<<dim3(89,4,4),256,0,stream>>>(W+OFF_CKV, W+OFF_POS, W+OFF_ATP);
    attnm_k<<<dim3(89,4),256,0,stream>>>(W+OFF_ATP, W+OFF_MHRAW);

    // fused mhsa-norm + CBAM + residual (BN4 inline)
    post_k<<<89,256,0,stream>>>(W+OFF_MHRAW, IN[22], IN[23], W+OFF_C4,
                                W+OFF_STATS+2304, IN[12], IN[13],
                                IN[24], IN[25], IN[26], IN[27], IN[28], IN[29], W+OFF_RES);

    // covariance metric + classifier
    covmu_k<<<dim3(5,64),256,0,stream>>>(W+OFF_RES, W+OFF_MU);
    cov_k<<<dim3(5,4,5),256,0,stream>>>(W+OFF_RES, W+OFF_MU, W+OFF_COV);
    qn_k<<<dim3(64,64),64,0,stream>>>(W+OFF_RES, W+OFF_QN);
    sim_k<<<dim3(64,4),256,0,stream>>>(W+OFF_QN, W+OFF_COV, W+OFF_SIM);
    cls_k<<<64,256,0,stream>>>(W+OFF_SIM, IN[30], OUT);
}